// Round 5
// baseline (491.673 us; speedup 1.0000x reference)
//
#include <hip/hip_runtime.h>
#include <hip/hip_bf16.h>

#define BATCH 8
#define CH    256
#define NTOK  4096

typedef __bf16 bf16_t;
typedef __bf16 bf16x8 __attribute__((ext_vector_type(8)));
typedef __bf16 bf16x4 __attribute__((ext_vector_type(4)));
typedef float  fx4    __attribute__((ext_vector_type(4)));

// async global->LDS, 16B per lane, dest = wave-uniform base + lane*16
#define GLOAD_LDS16(gptr, lptr) \
    __builtin_amdgcn_global_load_lds( \
        (const __attribute__((address_space(1))) void*)(gptr), \
        (__attribute__((address_space(3))) void*)(lptr), 16, 0, 0)

// MFMA lane layouts (gfx950, m89/m120-verified):
//   A[m=lane&15][k=quad*8+j], B[k=quad*8+j][n=lane&15], D[row=quad*4+reg][col=lane&15]

// ---------------------------------------------------------------------------
// W fp32 -> bf16 precvt into d_out scratch (attn overwrites out afterwards).
__global__ __launch_bounds__(256) void wcvt_kernel(
    const float* __restrict__ wq, const float* __restrict__ wk,
    const float* __restrict__ wv, bf16_t* __restrict__ wb)
{
    const int mat = blockIdx.y;
    const float* __restrict__ W = (mat == 0) ? wq : (mat == 1 ? wk : wv);
    const int idx = (blockIdx.x * 256 + threadIdx.x) * 4;
    const float4 v = *(const float4*)&W[idx];
    bf16x4 pk;
    pk[0] = (bf16_t)v.x; pk[1] = (bf16_t)v.y;
    pk[2] = (bf16_t)v.z; pk[3] = (bf16_t)v.w;
    *(bf16x4*)&wb[(size_t)mat * 65536 + idx] = pk;
}

// ---------------------------------------------------------------------------
// Projection v4 (UNCHANGED from R4 on purpose: with attn now faster, this
// kernel must surface in the rocprof top-5 so R6 gets its counters).
__global__ __launch_bounds__(256, 2) void proj_kernel(
    const float* __restrict__ x, const float* __restrict__ motion,
    const bf16_t* __restrict__ wb,
    const float* __restrict__ bq, const float* __restrict__ bk,
    const float* __restrict__ bv,
    bf16_t* __restrict__ qg, bf16_t* __restrict__ kg, bf16_t* __restrict__ vg)
{
    const int b  = blockIdx.x & 7;
    const int n0 = (blockIdx.x >> 3) * 64;

    __shared__ __align__(16) unsigned char smem[70656];
    bf16_t* Xt    = (bf16_t*)smem;              // [64][264] 16B-slot swizzled
    bf16_t* Mt    = (bf16_t*)(smem + 33792);    // [64][264] 16B-slot swizzled
    float*  biasL = (float*)(smem + 67584);     // [3][256]
    bf16_t* OutQK = (bf16_t*)smem;              // [64][264] alias
    bf16_t* OutV  = (bf16_t*)smem;              // [256][72] alias

    const int tid  = threadIdx.x;
    const int w    = tid >> 6;
    const int lane = tid & 63;
    const int l16  = lane & 15;
    const int quad = lane >> 4;

    biasL[tid]       = bq[tid];
    biasL[tid + 256] = bk[tid];
    biasL[tid + 512] = bv[tid];

    #pragma unroll
    for (int s = 0; s < 2; ++s) {
        const float* __restrict__ src = s ? motion : x;
        bf16_t* dst = s ? Mt : Xt;
        for (int it = 0; it < 16; ++it) {
            const int c  = it * 16 + (tid >> 4);
            const int j4 = (tid & 15) * 4;
            const float4 v = *(const float4*)&src[((size_t)b * CH + c) * NTOK + n0 + j4];
            const int g  = tid & 7;
            const int pc = (((c >> 3) ^ g) << 3) + (c & 7);
            dst[(j4 + 0) * 264 + pc] = (bf16_t)v.x;
            dst[(j4 + 1) * 264 + pc] = (bf16_t)v.y;
            dst[(j4 + 2) * 264 + pc] = (bf16_t)v.z;
            dst[(j4 + 3) * 264 + pc] = (bf16_t)v.w;
        }
    }
    __syncthreads();

    bf16x8 ax[8], am[8];
    {
        const int g = (4 * w + (l16 >> 2)) & 7;
        const bf16_t* xr = Xt + (w * 16 + l16) * 264;
        const bf16_t* mr = Mt + (w * 16 + l16) * 264;
        #pragma unroll
        for (int cs = 0; cs < 8; ++cs) {
            const int off = ((cs * 4 + quad) ^ g) << 3;
            ax[cs] = *(const bf16x8*)(xr + off);
            am[cs] = *(const bf16x8*)(mr + off);
        }
    }
    __syncthreads();

    fx4 acc[16];

    auto gemm = [&](const bf16x8* af, const bf16_t* __restrict__ Wm) {
        #pragma unroll
        for (int i = 0; i < 16; ++i) acc[i] = (fx4){0.f, 0.f, 0.f, 0.f};
        #pragma unroll
        for (int dp = 0; dp < 16; ++dp) {
            const bf16_t* wr = Wm + ((size_t)(dp * 16 + l16) << 8) + quad * 8;
            bf16x8 bfr[8];
            #pragma unroll
            for (int cs = 0; cs < 8; ++cs)
                bfr[cs] = *(const bf16x8*)(wr + cs * 32);
            #pragma unroll
            for (int cs = 0; cs < 8; ++cs)
                acc[dp] = __builtin_amdgcn_mfma_f32_16x16x32_bf16(af[cs], bfr[cs], acc[dp], 0, 0, 0);
        }
    };

    // ---- Q ----
    gemm(ax, wb);
    #pragma unroll
    for (int dp = 0; dp < 16; ++dp) {
        const int d = dp * 16 + l16;
        const float bb = biasL[d];
        #pragma unroll
        for (int r = 0; r < 4; ++r)
            OutQK[(w * 16 + quad * 4 + r) * 264 + d] = (bf16_t)((acc[dp][r] + bb) * 0.0625f);
    }
    __syncthreads();
    #pragma unroll
    for (int it = 0; it < 8; ++it) {
        const int n  = it * 8 + (tid >> 5);
        const int d8 = (tid & 31) * 8;
        const bf16x8 vv = *(const bf16x8*)&OutQK[n * 264 + d8];
        *(bf16x8*)&qg[((size_t)b * NTOK + n0 + n) * CH + d8] = vv;
    }

    // ---- K ----
    gemm(am, wb + 65536);
    __syncthreads();
    #pragma unroll
    for (int dp = 0; dp < 16; ++dp) {
        const int d = dp * 16 + l16;
        const float bb = biasL[256 + d];
        #pragma unroll
        for (int r = 0; r < 4; ++r)
            OutQK[(w * 16 + quad * 4 + r) * 264 + d] = (bf16_t)(acc[dp][r] + bb);
    }
    __syncthreads();
    #pragma unroll
    for (int it = 0; it < 8; ++it) {
        const int n  = it * 8 + (tid >> 5);
        const int d8 = (tid & 31) * 8;
        const bf16x8 vv = *(const bf16x8*)&OutQK[n * 264 + d8];
        *(bf16x8*)&kg[((size_t)b * NTOK + n0 + n) * CH + d8] = vv;
    }

    // ---- V ----
    gemm(am, wb + 131072);
    __syncthreads();
    #pragma unroll
    for (int dp = 0; dp < 16; ++dp) {
        const int d = dp * 16 + l16;
        const float bb = biasL[512 + d];
        bf16x4 pk;
        #pragma unroll
        for (int r = 0; r < 4; ++r)
            pk[r] = (bf16_t)(acc[dp][r] + bb);
        *(bf16x4*)&OutV[d * 72 + w * 16 + quad * 4] = pk;
    }
    __syncthreads();
    #pragma unroll
    for (int it = 0; it < 8; ++it) {
        const int d  = it * 32 + (tid >> 3);
        const int n8 = (tid & 7) * 8;
        const bf16x8 vv = *(const bf16x8*)&OutV[d * 72 + n8];
        *(bf16x8*)&vg[((size_t)b * CH + d) * NTOK + n0 + n8] = vv;
    }
}

// ---------------------------------------------------------------------------
// Attention v5: j-tile 64, V direct-from-L2 (1x, no LDS), K LDS double-buf.
// Wave roles: QK (ih=w&1 i-half, jh=w>>1 j-half): K-frag feeds 2 MFMAs.
//             PV (cq=w c-quarter, ALL 64 i): V-frag feeds 4 MFMAs (1x amp).
// Per tile t (64 j):
//   [0] vf(t): 8 global b128 loads (regs; compiler auto-emits vmcnt(8) at PV)
//   [1] stageK(t+1) -> Kn (8 DMA)
//   [2] vmcnt(16)  = drain K(t) only  [queue: K(t)8 | vf(t)8 | K(t+1)8]
//   [3] barrier A + ""::memory fence (P-WAR vs PV(t-1); K DMA cross-wave vis)
//   [4] QK: 16 kf ds_reads, 32 MFMA, 16 exp, packed P writes (stride 72)
//   [5] lgkmcnt(0); barrier B + fence (P RAW)
//   [6] PV: 8 pf ds_reads + 32 MFMA on vf(t) regs
// LDS traffic/tile: K-DMA 32K + kf 64K + P 8K+32K = 136K per 64 j (was 216K).
// LDS: K0@0 K1@32768 | P[64][72]@65536 | lred@74752 -> 75264 B (2 blk/CU)
__global__ __launch_bounds__(256, 2) void attn_kernel(
    const bf16_t* __restrict__ qg, const bf16_t* __restrict__ kg,
    const bf16_t* __restrict__ vg, float* __restrict__ out)
{
    const int b  = blockIdx.x & 7;     // batch -> XCD locality (K/V L2-resident)
    const int i0 = (blockIdx.x >> 3) * 64;

    __shared__ __align__(16) unsigned char smem[75264];
    bf16_t* const K0   = (bf16_t*)smem;               // [64][256] swizzled
    bf16_t* const K1   = (bf16_t*)(smem + 32768);
    bf16_t* const P    = (bf16_t*)(smem + 65536);     // [64][72]
    float*  const lred = (float*)(smem + 74752);      // [2][64]

    const int tid  = threadIdx.x;
    const int w    = tid >> 6;
    const int lane = tid & 63;
    const int l16  = lane & 15;
    const int quad = lane >> 4;
    const int ih   = w & 1;      // QK i-half
    const int jh   = w >> 1;     // QK j-half (32 of 64 j)
    const int cq   = w;          // PV c-quarter (64 c), all i
    const int w8   = w * 8;

    // Q A-frags: rows i0 + ih*32 + isub*16 + l16 (softmax scale folded in)
    bf16x8 qf[2][8];
    #pragma unroll
    for (int isub = 0; isub < 2; ++isub) {
        const bf16_t* qb = qg + ((size_t)b * NTOK + i0 + ih * 32 + isub * 16 + l16) * CH;
        #pragma unroll
        for (int cs = 0; cs < 8; ++cs)
            qf[isub][cs] = *(const bf16x8*)(qb + cs * 32 + quad * 8);
    }

    fx4 oacc[4][4];    // [cp][is]: c = cq*64+cp*16+quad*4+r, i = i0+is*16+l16
    #pragma unroll
    for (int i = 0; i < 4; ++i)
        #pragma unroll
        for (int j = 0; j < 4; ++j) oacc[i][j] = (fx4){0.f, 0.f, 0.f, 0.f};
    float rs0[4] = {0.f, 0.f, 0.f, 0.f};
    float rs1[4] = {0.f, 0.f, 0.f, 0.f};

    const int sxk = l16 & 7;                         // K read de-swizzle
    // V direct-load base: c = cq*64 + cp*16 + l16, j = j0 + ks*32 + quad*8
    const bf16_t* const vbase =
        vg + ((size_t)b * CH + cq * 64 + l16) * NTOK + quad * 8;

    auto stageK = [&](bf16_t* Kb, int t) {           // 64 rows, 8 DMA/wave
        const int j0 = t * 64;
        #pragma unroll
        for (int it = 0; it < 8; ++it) {
            const int N   = w8 + it;                 // 1 KiB chunk = rows 2N,2N+1
            const int kj  = 2 * N + (lane >> 5);
            const int ksl = (lane & 31) ^ (kj & 7);  // inverse-swizzled source
            GLOAD_LDS16(kg + (((size_t)b * NTOK + j0 + kj) << 8) + ksl * 8,
                        Kb + N * 512);
        }
    };

    stageK(K0, 0);   // prologue: queue = [K(0):8]

    auto tile = [&](bf16_t* const Kc, bf16_t* const Kn, const int t, const bool last) {
        const int j0 = t * 64;

        // [0] vf(t): 8 reg loads (FIRST, so compiler's auto-wait at PV = vmcnt(8))
        bf16x8 vf0[4], vf1[4];
        #pragma unroll
        for (int cp = 0; cp < 4; ++cp) {
            vf0[cp] = *(const bf16x8*)(vbase + (size_t)(cp * 16) * NTOK + j0);
            vf1[cp] = *(const bf16x8*)(vbase + (size_t)(cp * 16) * NTOK + j0 + 32);
        }
        // [1] K(t+1) -> Kn  (WAR ok: QK(t-1) kf reads drained before barrier B(t-1))
        if (!last) stageK(Kn, t + 1);
        // [2] drain K(t) only
        if (!last) { asm volatile("s_waitcnt vmcnt(16)" ::: "memory"); }
        else       { asm volatile("s_waitcnt vmcnt(8)"  ::: "memory"); }
        __builtin_amdgcn_s_barrier();      // A
        asm volatile("" ::: "memory");     // no LDS ops cross the barrier

        // [4] QK: S[ih*32 + isub*16 + quad*4+r][jh*32 + jp*16 + l16]
        fx4 s00 = (fx4){0.f,0.f,0.f,0.f}, s01 = (fx4){0.f,0.f,0.f,0.f};
        fx4 s10 = (fx4){0.f,0.f,0.f,0.f}, s11 = (fx4){0.f,0.f,0.f,0.f};
        {
            __builtin_amdgcn_s_setprio(1);
            const bf16_t* krow0 = Kc + (jh * 32 + l16) * 256;
            const bf16_t* krow1 = krow0 + 16 * 256;
            #pragma unroll
            for (int cs = 0; cs < 8; ++cs) {
                const int co = ((cs * 4 + quad) ^ sxk) << 3;
                const bf16x8 kf0 = *(const bf16x8*)(krow0 + co);
                const bf16x8 kf1 = *(const bf16x8*)(krow1 + co);
                s00 = __builtin_amdgcn_mfma_f32_16x16x32_bf16(qf[0][cs], kf0, s00, 0, 0, 0);
                s10 = __builtin_amdgcn_mfma_f32_16x16x32_bf16(qf[1][cs], kf0, s10, 0, 0, 0);
                s01 = __builtin_amdgcn_mfma_f32_16x16x32_bf16(qf[0][cs], kf1, s01, 0, 0, 0);
                s11 = __builtin_amdgcn_mfma_f32_16x16x32_bf16(qf[1][cs], kf1, s11, 0, 0, 0);
            }
            __builtin_amdgcn_s_setprio(0);
        }
        // exp + rowsums + packed P writes (u32 pairs; conflict-free banks)
        #pragma unroll
        for (int jp = 0; jp < 2; ++jp) {
            const fx4 sa = jp ? s01 : s00;
            const fx4 sb = jp ? s11 : s10;
            bf16_t* prow = P + (ih * 32 + quad * 4) * 72 + jh * 32 + jp * 16 + (l16 & ~1);
            #pragma unroll
            for (int r = 0; r < 4; ++r) {
                const float p0 = __expf(sa[r]);
                const float p1 = __expf(sb[r]);
                rs0[r] += p0;
                rs1[r] += p1;
                const float n0f = __shfl_xor(p0, 1);
                const float n1f = __shfl_xor(p1, 1);
                unsigned int pk0, pk1;
                asm("v_cvt_pk_bf16_f32 %0, %1, %2" : "=v"(pk0) : "v"(p0), "v"(n0f));
                asm("v_cvt_pk_bf16_f32 %0, %1, %2" : "=v"(pk1) : "v"(p1), "v"(n1f));
                if (!(l16 & 1)) {
                    *(unsigned int*)(prow + r * 72)            = pk0;  // isub 0
                    *(unsigned int*)(prow + r * 72 + 16 * 72)  = pk1;  // isub 1
                }
            }
        }
        // [5] P visible block-wide (K(t+1)/vf left flying)
        asm volatile("s_waitcnt lgkmcnt(0)" ::: "memory");
        __builtin_amdgcn_s_barrier();      // B
        asm volatile("" ::: "memory");

        // [6] PV: O[cq*64 +..][all i] += V * P^T; vf(t) regs, pf from LDS
        {
            __builtin_amdgcn_s_setprio(1);
            #pragma unroll
            for (int is = 0; is < 4; ++is) {
                const bf16_t* pr = P + (is * 16 + l16) * 72 + quad * 8;
                const bf16x8 pf0 = *(const bf16x8*)(pr);
                const bf16x8 pf1 = *(const bf16x8*)(pr + 32);
                #pragma unroll
                for (int cp = 0; cp < 4; ++cp) {
                    oacc[cp][is] = __builtin_amdgcn_mfma_f32_16x16x32_bf16(vf0[cp], pf0, oacc[cp][is], 0, 0, 0);
                    oacc[cp][is] = __builtin_amdgcn_mfma_f32_16x16x32_bf16(vf1[cp], pf1, oacc[cp][is], 0, 0, 0);
                }
            }
            __builtin_amdgcn_s_setprio(0);
        }
    };

    #pragma unroll 1
    for (int t = 0; t < 62; t += 2) {
        tile(K0, K1, t,     false);
        tile(K1, K0, t + 1, false);
    }
    tile(K0, K1, 62, false);
    tile(K1, K0, 63, true);

    // rowsum: butterfly over 16 j-lanes, combine jh halves via LDS
    #pragma unroll
    for (int r = 0; r < 4; ++r) {
        float v0 = rs0[r], v1 = rs1[r];
        v0 += __shfl_xor(v0, 1); v0 += __shfl_xor(v0, 2);
        v0 += __shfl_xor(v0, 4); v0 += __shfl_xor(v0, 8);
        v1 += __shfl_xor(v1, 1); v1 += __shfl_xor(v1, 2);
        v1 += __shfl_xor(v1, 4); v1 += __shfl_xor(v1, 8);
        rs0[r] = v0; rs1[r] = v1;
    }
    __syncthreads();
    if (l16 == 0) {
        #pragma unroll
        for (int r = 0; r < 4; ++r) {
            lred[jh * 64 + ih * 32 + quad * 4 + r]      = rs0[r];
            lred[jh * 64 + ih * 32 + 16 + quad * 4 + r] = rs1[r];
        }
    }
    __syncthreads();

    float linv[4];
    #pragma unroll
    for (int is = 0; is < 4; ++is) {
        const int row = is * 16 + l16;
        linv[is] = 1.0f / (lred[row] + lred[64 + row]);
    }

    // O store: c = cq*64 + cp*16 + quad*4 + r, i = i0 + is*16 + l16
    const size_t obase = ((size_t)b * CH + cq * 64) * NTOK + i0 + l16;
    #pragma unroll
    for (int cp = 0; cp < 4; ++cp) {
        #pragma unroll
        for (int is = 0; is < 4; ++is) {
            #pragma unroll
            for (int r = 0; r < 4; ++r) {
                out[obase + (size_t)(cp * 16 + quad * 4 + r) * NTOK + is * 16] =
                    oacc[cp][is][r] * linv[is];
            }
        }
    }
}

// ---------------------------------------------------------------------------
extern "C" void kernel_launch(void* const* d_in, const int* in_sizes, int n_in,
                              void* d_out, int out_size, void* d_ws, size_t ws_size,
                              hipStream_t stream) {
    const float* x  = (const float*)d_in[0];
    const float* mi = (const float*)d_in[1];
    const float* wq = (const float*)d_in[2];
    const float* bq = (const float*)d_in[3];
    const float* wk = (const float*)d_in[4];
    const float* bk = (const float*)d_in[5];
    const float* wv = (const float*)d_in[6];
    const float* bv = (const float*)d_in[7];

    bf16_t* qg = (bf16_t*)d_ws;
    bf16_t* kg = qg + (size_t)BATCH * NTOK * CH;
    bf16_t* vg = kg + (size_t)BATCH * NTOK * CH;
    bf16_t* wb = (bf16_t*)d_out;   // scratch: fully overwritten by attn later

    dim3 wgrid(64, 3);
    wcvt_kernel<<<wgrid, 256, 0, stream>>>(wq, wk, wv, wb);

    proj_kernel<<<BATCH * (NTOK / 64), 256, 0, stream>>>(x, mi, wb, bq, bk, bv, qg, kg, vg);

    attn_kernel<<<BATCH * (NTOK / 64), 256, 0, stream>>>(qg, kg, vg, (float*)d_out);
}